// Round 8
// baseline (679.376 us; speedup 1.0000x reference)
//
#include <hip/hip_runtime.h>
#include <math.h>

#define N_NODES 60000
#define N_EDGES 600000
#define B_GRAPHS 512
#define DIM 128
#define RBF_R 30
#define NLAYERS 3
#define NBINS 1024

typedef __attribute__((ext_vector_type(8))) short bf16x8;
typedef __attribute__((ext_vector_type(4))) float f32x4;

__device__ __forceinline__ float sp05(float x) {
    float bx = 0.5f * x;
    return bx > 14.0f ? x : 2.0f * log1pf(expf(bx));
}
__device__ __forceinline__ float sp1(float x) {
    return x > 20.0f ? x : log1pf(expf(x));
}
__device__ __forceinline__ unsigned short f2bf(float f) {
    unsigned int u = __float_as_uint(f);
    unsigned int r = u + 0x7FFFu + ((u >> 16) & 1u);  // RNE
    return (unsigned short)(r >> 16);
}
__device__ __forceinline__ float bf2f(unsigned int s) {
    return __uint_as_float(s << 16);
}

// ---------------- one-time conversion (fused) ----------------
// Fragment-order: each MFMA B-fragment (64 lanes x 16B) stored contiguously.
__global__ void k_conv(const float* __restrict__ Wn1, const float* __restrict__ Wn2,
                       const float* __restrict__ Wn3, const float* __restrict__ Wr1,
                       unsigned short* __restrict__ WtF, unsigned short* __restrict__ Wr1tF) {
    int i = blockIdx.x * 256 + threadIdx.x;
    if (i < 9 * 16384) {
        int mat = i >> 14, r = i & 16383;
        int frag = r >> 9, within = r & 511;
        int ks = frag >> 3, ntile = frag & 7;
        int lane = within >> 3, j = within & 7;
        int q = lane >> 4, l16 = lane & 15;
        int n = ntile * 16 + l16;
        int k = ks * 32 + q * 8 + j;
        const float* src = (mat < 3) ? (Wn1 + (size_t)mat * 16384)
                         : (mat < 6) ? (Wn2 + (size_t)(mat - 3) * 16384)
                                     : (Wn3 + (size_t)(mat - 6) * 16384);
        WtF[i] = f2bf(src[k * 128 + n]);
    } else {
        int ii = i - 9 * 16384;
        if (ii < 32768) {
            int frag = ii >> 9, within = ii & 511;
            int lvl = frag >> 4, ks = (frag >> 2) & 3, ntile = frag & 3;
            int lane = within >> 3, j = within & 7;
            int q = lane >> 4, l16 = lane & 15;
            int n = ntile * 16 + l16;
            int k = lvl * 128 + ks * 32 + q * 8 + j;
            Wr1tF[ii] = f2bf(Wr1[k * 64 + n]);
        }
    }
}

// h0 = node_emb[atom_type] (fp32 + bf16 copies)
__global__ void k_embed(const int* __restrict__ atom_type,
                        const float* __restrict__ node_emb,
                        float* __restrict__ h0, unsigned short* __restrict__ hb0) {
    int i = blockIdx.x * blockDim.x + threadIdx.x;
    if (i >= N_NODES * DIM) return;
    int n = i >> 7, d = i & 127;
    float v = node_emb[atom_type[n] * DIM + d];
    h0[i] = v;
    hb0[i] = f2bf(v);
}

// ---------------- CSR build ----------------

__global__ void k_hist(const int* __restrict__ dst, int* __restrict__ counts) {
    int e = blockIdx.x * blockDim.x + threadIdx.x;
    if (e >= N_EDGES) return;
    atomicAdd(&counts[dst[e]], 1);
}

// Single-block two-level exclusive scan: counts[60000] -> offsets[60001].
__global__ void k_scan_all(const int* __restrict__ counts, int* __restrict__ offsets) {
    __shared__ int sums[1024];
    int tid = threadIdx.x;
    const int CPT = 60;   // 1024*60 >= 60000
    int base = tid * CPT;
    int s = 0;
#pragma unroll 4
    for (int i = 0; i < CPT; ++i) {
        int idx = base + i;
        if (idx < N_NODES) s += counts[idx];
    }
    sums[tid] = s;
    __syncthreads();
    for (int off = 1; off < 1024; off <<= 1) {
        int v = (tid >= off) ? sums[tid - off] : 0;
        __syncthreads();
        sums[tid] += v;
        __syncthreads();
    }
    int run = (tid == 0) ? 0 : sums[tid - 1];
    for (int i = 0; i < CPT; ++i) {
        int idx = base + i;
        if (idx < N_NODES) { int c = counts[idx]; offsets[idx] = run; run += c; }
    }
    if (tid == 1023) offsets[N_NODES] = N_EDGES;
}

// Fill perm-ordered meta: one uint2 per edge = (src, bin<<16 | w_fixed16).
__global__ void k_fill(const int* __restrict__ src, const int* __restrict__ dst,
                       const float* __restrict__ dist,
                       const int* __restrict__ offsets, int* __restrict__ cnt2,
                       uint2* __restrict__ meta) {
    int e = blockIdx.x * blockDim.x + threadIdx.x;
    if (e >= N_EDGES) return;
    int d = dst[e];
    int pos = offsets[d] + atomicAdd(&cnt2[d], 1);
    float x = dist[e];
    float p = x * ((float)NBINS / 10.0f);
    int bin = (int)p;
    if (bin > NBINS - 1) bin = NBINS - 1;
    float w = p - (float)bin;
    int wq = (int)(w * 65535.0f + 0.5f);
    if (wq > 65535) wq = 65535;
    meta[pos] = make_uint2((unsigned)src[e], ((unsigned)bin << 16) | (unsigned)wq);
}

// ---------------- tables (all layers upfront) ----------------

// layer = blockIdx.x / (NBINS+1), bin = blockIdx.x % (NBINS+1)
__global__ void k_table_all(const float* __restrict__ Wc1, const float* __restrict__ bc1,
                            const float* __restrict__ Wc2, const float* __restrict__ bc2,
                            const float* __restrict__ Wc3, const float* __restrict__ bc3,
                            unsigned short* __restrict__ tableb) {
    __shared__ float t[DIM];
    __shared__ float u[DIM];
    int lyr = blockIdx.x / (NBINS + 1);
    int b = blockIdx.x % (NBINS + 1);
    int d = threadIdx.x;
    const float* wc1 = Wc1 + (size_t)lyr * RBF_R * DIM;
    const float* wc2 = Wc2 + (size_t)lyr * DIM * DIM;
    const float* wc3 = Wc3 + (size_t)lyr * DIM * DIM;
    float dist = (float)b * (10.0f / (float)NBINS);
    const float gap = 10.0f / 29.0f;
    float acc = bc1[lyr * DIM + d];
#pragma unroll
    for (int k = 0; k < RBF_R; ++k) {
        float c = (float)k * (10.0f / 29.0f);
        float df = dist - c;
        acc += expf(-df * df / gap) * wc1[k * DIM + d];
    }
    t[d] = sp05(acc);
    __syncthreads();
    acc = bc2[lyr * DIM + d];
#pragma unroll 8
    for (int k = 0; k < DIM; ++k) acc += t[k] * wc2[k * DIM + d];
    u[d] = acc;
    __syncthreads();
    acc = bc3[lyr * DIM + d];
#pragma unroll 8
    for (int k = 0; k < DIM; ++k) acc += u[k] * wc3[k * DIM + d];
    tableb[((size_t)lyr * (NBINS + 1) + b) * DIM + d] = f2bf(acc);
}

// Pack (a, delta) for all 3 layers: packed[lyr][bin][dim].
__global__ void k_pack_all(const unsigned short* __restrict__ tableb,
                           unsigned int* __restrict__ packed) {
    int i = blockIdx.x * 256 + threadIdx.x;   // 3*NBINS*128
    int lyr = i / (NBINS * DIM);
    int r = i % (NBINS * DIM);
    const unsigned short* tb = tableb + (size_t)lyr * (NBINS + 1) * DIM;
    float a = bf2f(tb[r]);
    float b = bf2f(tb[r + DIM]);
    packed[i] = (unsigned int)f2bf(a) | ((unsigned int)f2bf(b - a) << 16);
}

// ---------------- per-layer kernels ----------------

// MFMA GEMM: Cb = bf16( Ab @ W^T + bias + 1 ). Fragment-order B.
__global__ __launch_bounds__(256) void k_gemm_g(const unsigned short* __restrict__ Ab,
                                                const unsigned short* __restrict__ WtF,
                                                const float* __restrict__ bias,
                                                unsigned short* __restrict__ Cb) {
    int tid = threadIdx.x;
    int wave = tid >> 6, lane = tid & 63;
    int q = lane >> 4, l16 = lane & 15;
    int mhalf = wave & 1, nhalf = wave >> 1;
    int rb = blockIdx.x * 64 + mhalf * 32;
    int c0 = nhalf * 64;
    bf16x8 bfrag[4][4];
#pragma unroll
    for (int ks = 0; ks < 4; ++ks)
#pragma unroll
        for (int nt = 0; nt < 4; ++nt)
            bfrag[ks][nt] = *(const bf16x8*)&WtF[(size_t)(ks * 8 + nhalf * 4 + nt) * 512 + lane * 8];
    f32x4 acc[2][4] = {};
#pragma unroll
    for (int ks = 0; ks < 4; ++ks)
#pragma unroll
        for (int mt = 0; mt < 2; ++mt) {
            int m = rb + mt * 16 + l16;
            if (m > N_NODES - 1) m = N_NODES - 1;
            bf16x8 a = *(const bf16x8*)&Ab[(size_t)m * 128 + ks * 32 + q * 8];
#pragma unroll
            for (int nt = 0; nt < 4; ++nt)
                acc[mt][nt] = __builtin_amdgcn_mfma_f32_16x16x32_bf16(a, bfrag[ks][nt], acc[mt][nt], 0, 0, 0);
        }
#pragma unroll
    for (int mt = 0; mt < 2; ++mt)
#pragma unroll
        for (int nt = 0; nt < 4; ++nt) {
            int col = c0 + nt * 16 + l16;
            float b = bias[col] + 1.0f;
#pragma unroll
            for (int r = 0; r < 4; ++r) {
                int row = rb + mt * 16 + q * 4 + r;
                if (row < N_NODES) Cb[(size_t)row * 128 + col] = f2bf(acc[mt][nt][r] + b);
            }
        }
}

// Gather: wave-per-node (4 nodes / 256-block). Lane owns dims {2*lane, 2*lane+1}.
__global__ __launch_bounds__(256) void k_gather(
    const int* __restrict__ offsets, const uint2* __restrict__ meta,
    const unsigned int* __restrict__ packed, const unsigned short* __restrict__ gb,
    unsigned short* __restrict__ nodeb) {
    int wave = threadIdx.x >> 6, lane = threadIdx.x & 63;
    int n = blockIdx.x * 4 + wave;
    int beg = offsets[n], end = offsets[n + 1];
    int off = lane * 2;
    const float ws = 1.0f / 65535.0f;
    float acc0 = 0.f, acc1 = 0.f, acc2 = 0.f, acc3 = 0.f;
    int j = beg;
    for (; j + 4 <= end; j += 4) {
        uint2 m0 = meta[j], m1 = meta[j + 1], m2 = meta[j + 2], m3 = meta[j + 3];
        uint2 p0 = *(const uint2*)&packed[(size_t)(m0.y >> 16) * DIM + off];
        uint2 p1 = *(const uint2*)&packed[(size_t)(m1.y >> 16) * DIM + off];
        uint2 p2 = *(const uint2*)&packed[(size_t)(m2.y >> 16) * DIM + off];
        uint2 p3 = *(const uint2*)&packed[(size_t)(m3.y >> 16) * DIM + off];
        unsigned int g0 = *(const unsigned int*)&gb[(size_t)m0.x * DIM + off];
        unsigned int g1 = *(const unsigned int*)&gb[(size_t)m1.x * DIM + off];
        unsigned int g2 = *(const unsigned int*)&gb[(size_t)m2.x * DIM + off];
        unsigned int g3 = *(const unsigned int*)&gb[(size_t)m3.x * DIM + off];
        float w0 = (float)(m0.y & 0xffff) * ws;
        float w1 = (float)(m1.y & 0xffff) * ws;
        float w2 = (float)(m2.y & 0xffff) * ws;
        float w3 = (float)(m3.y & 0xffff) * ws;
        acc0 += bf2f(g0 & 0xffff) * (bf2f(p0.x & 0xffff) + w0 * bf2f(p0.x >> 16));
        acc1 += bf2f(g0 >> 16)    * (bf2f(p0.y & 0xffff) + w0 * bf2f(p0.y >> 16));
        acc2 += bf2f(g1 & 0xffff) * (bf2f(p1.x & 0xffff) + w1 * bf2f(p1.x >> 16));
        acc3 += bf2f(g1 >> 16)    * (bf2f(p1.y & 0xffff) + w1 * bf2f(p1.y >> 16));
        acc0 += bf2f(g2 & 0xffff) * (bf2f(p2.x & 0xffff) + w2 * bf2f(p2.x >> 16));
        acc1 += bf2f(g2 >> 16)    * (bf2f(p2.y & 0xffff) + w2 * bf2f(p2.y >> 16));
        acc2 += bf2f(g3 & 0xffff) * (bf2f(p3.x & 0xffff) + w3 * bf2f(p3.x >> 16));
        acc3 += bf2f(g3 >> 16)    * (bf2f(p3.y & 0xffff) + w3 * bf2f(p3.y >> 16));
    }
    for (; j < end; ++j) {
        uint2 m0 = meta[j];
        uint2 p0 = *(const uint2*)&packed[(size_t)(m0.y >> 16) * DIM + off];
        unsigned int g0 = *(const unsigned int*)&gb[(size_t)m0.x * DIM + off];
        float w0 = (float)(m0.y & 0xffff) * ws;
        acc0 += bf2f(g0 & 0xffff) * (bf2f(p0.x & 0xffff) + w0 * bf2f(p0.x >> 16));
        acc1 += bf2f(g0 >> 16)    * (bf2f(p0.y & 0xffff) + w0 * bf2f(p0.y >> 16));
    }
    acc0 += acc2; acc1 += acc3;
    unsigned int o = (unsigned int)f2bf(acc0) | ((unsigned int)f2bf(acc1) << 16);
    *(unsigned int*)&nodeb[(size_t)n * DIM + off] = o;
}

// h_out = h_in + sp05(nodeb@W2^T + b2) @ W3^T + b3 ; fp32 + bf16 outputs.
__global__ __launch_bounds__(256) void k_node_update(
    const unsigned short* __restrict__ nodeb,
    const unsigned short* __restrict__ W2tF, const float* __restrict__ b2,
    const unsigned short* __restrict__ W3tF, const float* __restrict__ b3,
    const float* __restrict__ h_in, float* __restrict__ h_out,
    unsigned short* __restrict__ hb_out) {
    __shared__ unsigned short ts[64][136];
    int tid = threadIdx.x;
    int wave = tid >> 6, lane = tid & 63;
    int q = lane >> 4, l16 = lane & 15;
    int mhalf = wave & 1, nhalf = wave >> 1;
    int rb = blockIdx.x * 64 + mhalf * 32;
    int c0 = nhalf * 64;

    bf16x8 bfrag[4][4];
#pragma unroll
    for (int ks = 0; ks < 4; ++ks)
#pragma unroll
        for (int nt = 0; nt < 4; ++nt)
            bfrag[ks][nt] = *(const bf16x8*)&W2tF[(size_t)(ks * 8 + nhalf * 4 + nt) * 512 + lane * 8];
    f32x4 acc[2][4] = {};
#pragma unroll
    for (int ks = 0; ks < 4; ++ks)
#pragma unroll
        for (int mt = 0; mt < 2; ++mt) {
            int m = rb + mt * 16 + l16;
            if (m > N_NODES - 1) m = N_NODES - 1;
            bf16x8 a = *(const bf16x8*)&nodeb[(size_t)m * 128 + ks * 32 + q * 8];
#pragma unroll
            for (int nt = 0; nt < 4; ++nt)
                acc[mt][nt] = __builtin_amdgcn_mfma_f32_16x16x32_bf16(a, bfrag[ks][nt], acc[mt][nt], 0, 0, 0);
        }
#pragma unroll
    for (int mt = 0; mt < 2; ++mt)
#pragma unroll
        for (int nt = 0; nt < 4; ++nt) {
            int col = c0 + nt * 16 + l16;
            float b = b2[col];
#pragma unroll
            for (int r = 0; r < 4; ++r) {
                int lrow = mhalf * 32 + mt * 16 + q * 4 + r;
                ts[lrow][col] = f2bf(sp05(acc[mt][nt][r] + b));
            }
        }
    __syncthreads();
#pragma unroll
    for (int ks = 0; ks < 4; ++ks)
#pragma unroll
        for (int nt = 0; nt < 4; ++nt)
            bfrag[ks][nt] = *(const bf16x8*)&W3tF[(size_t)(ks * 8 + nhalf * 4 + nt) * 512 + lane * 8];
#pragma unroll
    for (int mt = 0; mt < 2; ++mt)
#pragma unroll
        for (int nt = 0; nt < 4; ++nt) acc[mt][nt] = (f32x4){0.f, 0.f, 0.f, 0.f};
#pragma unroll
    for (int ks = 0; ks < 4; ++ks)
#pragma unroll
        for (int mt = 0; mt < 2; ++mt) {
            int lrow = mhalf * 32 + mt * 16 + l16;
            bf16x8 a = *(const bf16x8*)&ts[lrow][ks * 32 + q * 8];
#pragma unroll
            for (int nt = 0; nt < 4; ++nt)
                acc[mt][nt] = __builtin_amdgcn_mfma_f32_16x16x32_bf16(a, bfrag[ks][nt], acc[mt][nt], 0, 0, 0);
        }
#pragma unroll
    for (int mt = 0; mt < 2; ++mt)
#pragma unroll
        for (int nt = 0; nt < 4; ++nt) {
            int col = c0 + nt * 16 + l16;
            float b = b3[col];
#pragma unroll
            for (int r = 0; r < 4; ++r) {
                int row = rb + mt * 16 + q * 4 + r;
                if (row < N_NODES) {
                    size_t idx = (size_t)row * 128 + col;
                    float v = h_in[idx] + acc[mt][nt][r] + b;
                    h_out[idx] = v;
                    hb_out[idx] = f2bf(v);
                }
            }
        }
}

// Readout: round-5 best config — 128 rows/block (2 m-tiles/wave), global
// fragment-order B loads, no LDS. Measured 75 us; LDS staging (r7) and
// 64-row blocks (r6) both regressed.
__global__ __launch_bounds__(256) void k_readout(
    const unsigned short* __restrict__ hb0, const unsigned short* __restrict__ hb1,
    const unsigned short* __restrict__ hb2, const unsigned short* __restrict__ hb3,
    const unsigned short* __restrict__ Wr1tF, const float* __restrict__ br1,
    const float* __restrict__ Wr2, const float* __restrict__ br2,
    const int* __restrict__ graph_ids, float* __restrict__ out) {
    int tid = threadIdx.x;
    int wave = tid >> 6, lane = tid & 63;
    int q = lane >> 4, l16 = lane & 15;
    int rb0 = blockIdx.x * 128 + wave * 16;   // m-tile mt at rb0 + mt*64
    const unsigned short* hbs[4] = {hb0, hb1, hb2, hb3};
    f32x4 acc[2][4] = {};
    for (int lvl = 0; lvl < 4; ++lvl) {
        bf16x8 bfrag[4][4];
#pragma unroll
        for (int ks = 0; ks < 4; ++ks)
#pragma unroll
            for (int nt = 0; nt < 4; ++nt)
                bfrag[ks][nt] = *(const bf16x8*)&Wr1tF[(size_t)((lvl * 4 + ks) * 4 + nt) * 512 + lane * 8];
        const unsigned short* Ab = hbs[lvl];
#pragma unroll
        for (int ks = 0; ks < 4; ++ks)
#pragma unroll
            for (int mt = 0; mt < 2; ++mt) {
                int m = rb0 + mt * 64 + l16;
                if (m > N_NODES - 1) m = N_NODES - 1;
                bf16x8 a = *(const bf16x8*)&Ab[(size_t)m * 128 + ks * 32 + q * 8];
#pragma unroll
                for (int nt = 0; nt < 4; ++nt)
                    acc[mt][nt] = __builtin_amdgcn_mfma_f32_16x16x32_bf16(a, bfrag[ks][nt], acc[mt][nt], 0, 0, 0);
            }
    }
    float brr = br2[0];
#pragma unroll
    for (int mt = 0; mt < 2; ++mt) {
        float partial[4] = {0.f, 0.f, 0.f, 0.f};
#pragma unroll
        for (int nt = 0; nt < 4; ++nt) {
            int col = nt * 16 + l16;
            float b = br1[col];
            float w = Wr2[col];
#pragma unroll
            for (int r = 0; r < 4; ++r) partial[r] += sp1(acc[mt][nt][r] + b) * w;
        }
#pragma unroll
        for (int r = 0; r < 4; ++r) {
            float v = partial[r];
            v += __shfl_xor(v, 1); v += __shfl_xor(v, 2);
            v += __shfl_xor(v, 4); v += __shfl_xor(v, 8);
            if (l16 == 0) {
                int row = rb0 + mt * 64 + q * 4 + r;
                if (row < N_NODES) atomicAdd(&out[graph_ids[row]], v + brr);
            }
        }
    }
}

extern "C" void kernel_launch(void* const* d_in, const int* in_sizes, int n_in,
                              void* d_out, int out_size, void* d_ws, size_t ws_size,
                              hipStream_t stream) {
    const int* atom_type   = (const int*)d_in[0];
    const int* src         = (const int*)d_in[1];
    const int* dst         = (const int*)d_in[2];
    const int* graph_ids   = (const int*)d_in[3];
    const float* dist      = (const float*)d_in[4];
    const float* node_emb  = (const float*)d_in[5];
    const float* W_n1 = (const float*)d_in[6];  const float* b_n1 = (const float*)d_in[7];
    const float* W_c1 = (const float*)d_in[8];  const float* b_c1 = (const float*)d_in[9];
    const float* W_c2 = (const float*)d_in[10]; const float* b_c2 = (const float*)d_in[11];
    const float* W_c3 = (const float*)d_in[12]; const float* b_c3 = (const float*)d_in[13];
    const float* W_n2 = (const float*)d_in[14]; const float* b_n2 = (const float*)d_in[15];
    const float* W_n3 = (const float*)d_in[16]; const float* b_n3 = (const float*)d_in[17];
    const float* W_r1 = (const float*)d_in[18]; const float* b_r1 = (const float*)d_in[19];
    const float* W_r2 = (const float*)d_in[20]; const float* b_r2 = (const float*)d_in[21];
    float* out = (float*)d_out;

    size_t ND = (size_t)N_NODES * DIM;   // 7,680,000
    // float region
    float* h_even = (float*)d_ws;
    float* h_odd  = h_even + ND;
    // uint2 meta (8-B aligned)
    uint2* meta   = (uint2*)(h_odd + ND);               // N_EDGES
    // int region
    int* offsets  = (int*)(meta + N_EDGES);             // 60008 (padded)
    int* counts   = offsets + 60008;                    // 60000
    int* cnt2     = counts + N_NODES;                   // 60000
    unsigned int* packed = (unsigned int*)(cnt2 + N_NODES);  // 3*NBINS*128
    // ushort region
    unsigned short* hb0    = (unsigned short*)(packed + (size_t)3 * NBINS * DIM);
    unsigned short* hb1    = hb0 + ND;
    unsigned short* hb2    = hb1 + ND;
    unsigned short* hb3    = hb2 + ND;
    unsigned short* gb     = hb3 + ND;
    unsigned short* nodeb  = gb + ND;
    unsigned short* tableb = nodeb + ND;                // 3*(NBINS+1)*128
    unsigned short* WtF    = tableb + (size_t)3 * (NBINS + 1) * DIM;  // 9*16384
    unsigned short* Wr1tF  = WtF + 9 * 16384;           // 32768

    unsigned short* hbp[4] = {hb0, hb1, hb2, hb3};
    float* hcur = h_even;
    float* hnext = h_odd;

    hipMemsetAsync(out, 0, B_GRAPHS * sizeof(float), stream);
    hipMemsetAsync(counts, 0, 2 * N_NODES * sizeof(int), stream);

    // one-time setup (all before the layer loop; tables depend only on weights)
    k_conv<<<(9 * 16384 + 32768 + 255) / 256, 256, 0, stream>>>(
        W_n1, W_n2, W_n3, W_r1, WtF, Wr1tF);
    k_embed<<<(N_NODES * DIM) / 256, 256, 0, stream>>>(atom_type, node_emb, h_even, hb0);
    k_table_all<<<3 * (NBINS + 1), DIM, 0, stream>>>(
        W_c1, b_c1, W_c2, b_c2, W_c3, b_c3, tableb);
    k_pack_all<<<(3 * NBINS * DIM) / 256, 256, 0, stream>>>(tableb, packed);

    // CSR build (dst-sorted edge meta)
    k_hist<<<(N_EDGES + 255) / 256, 256, 0, stream>>>(dst, counts);
    k_scan_all<<<1, 1024, 0, stream>>>(counts, offsets);
    k_fill<<<(N_EDGES + 255) / 256, 256, 0, stream>>>(src, dst, dist, offsets, cnt2, meta);

    int gblocks = (N_NODES + 63) / 64;      // 938
    int rblocks = (N_NODES + 127) / 128;    // 469
    for (int i = 0; i < NLAYERS; ++i) {
        k_gemm_g<<<gblocks, 256, 0, stream>>>(
            hbp[i], WtF + (size_t)i * 16384, b_n1 + (size_t)i * DIM, gb);
        k_gather<<<N_NODES / 4, 256, 0, stream>>>(
            offsets, meta, packed + (size_t)i * NBINS * DIM, gb, nodeb);
        k_node_update<<<gblocks, 256, 0, stream>>>(
            nodeb, WtF + (size_t)(3 + i) * 16384, b_n2 + (size_t)i * DIM,
            WtF + (size_t)(6 + i) * 16384, b_n3 + (size_t)i * DIM,
            hcur, hnext, hbp[i + 1]);
        float* tmp = hcur; hcur = hnext; hnext = tmp;
    }
    k_readout<<<rblocks, 256, 0, stream>>>(
        hb0, hb1, hb2, hb3, Wr1tF, b_r1, W_r2, b_r2, graph_ids, out);
}

// Round 9
// 586.567 us; speedup vs baseline: 1.1582x; 1.1582x over previous
//
#include <hip/hip_runtime.h>
#include <math.h>

#define N_NODES 60000
#define N_EDGES 600000
#define B_GRAPHS 512
#define DIM 128
#define RBF_R 30
#define NLAYERS 3
#define NBINS 1024
#define CHUNK 512
#define NCHUNK ((N_NODES + CHUNK - 1) / CHUNK)   // 118

typedef __attribute__((ext_vector_type(8))) short bf16x8;
typedef __attribute__((ext_vector_type(4))) float f32x4;

__device__ __forceinline__ float sp05(float x) {
    float bx = 0.5f * x;
    return bx > 14.0f ? x : 2.0f * log1pf(expf(bx));
}
__device__ __forceinline__ float sp1(float x) {
    return x > 20.0f ? x : log1pf(expf(x));
}
__device__ __forceinline__ unsigned short f2bf(float f) {
    unsigned int u = __float_as_uint(f);
    unsigned int r = u + 0x7FFFu + ((u >> 16) & 1u);  // RNE
    return (unsigned short)(r >> 16);
}
__device__ __forceinline__ float bf2f(unsigned int s) {
    return __uint_as_float(s << 16);
}

// ---------------- one-time conversion (fused) ----------------
// Fragment-order: each MFMA B-fragment (64 lanes x 16B) stored contiguously.
__global__ void k_conv(const float* __restrict__ Wn1, const float* __restrict__ Wn2,
                       const float* __restrict__ Wn3, const float* __restrict__ Wr1,
                       unsigned short* __restrict__ WtF, unsigned short* __restrict__ Wr1tF) {
    int i = blockIdx.x * 256 + threadIdx.x;
    if (i < 9 * 16384) {
        int mat = i >> 14, r = i & 16383;
        int frag = r >> 9, within = r & 511;
        int ks = frag >> 3, ntile = frag & 7;
        int lane = within >> 3, j = within & 7;
        int q = lane >> 4, l16 = lane & 15;
        int n = ntile * 16 + l16;
        int k = ks * 32 + q * 8 + j;
        const float* src = (mat < 3) ? (Wn1 + (size_t)mat * 16384)
                         : (mat < 6) ? (Wn2 + (size_t)(mat - 3) * 16384)
                                     : (Wn3 + (size_t)(mat - 6) * 16384);
        WtF[i] = f2bf(src[k * 128 + n]);
    } else {
        int ii = i - 9 * 16384;
        if (ii < 32768) {
            int frag = ii >> 9, within = ii & 511;
            int lvl = frag >> 4, ks = (frag >> 2) & 3, ntile = frag & 3;
            int lane = within >> 3, j = within & 7;
            int q = lane >> 4, l16 = lane & 15;
            int n = ntile * 16 + l16;
            int k = lvl * 128 + ks * 32 + q * 8 + j;
            Wr1tF[ii] = f2bf(Wr1[k * 64 + n]);
        }
    }
}

// h0 = node_emb[atom_type] (fp32 + bf16 copies)
__global__ void k_embed(const int* __restrict__ atom_type,
                        const float* __restrict__ node_emb,
                        float* __restrict__ h0, unsigned short* __restrict__ hb0) {
    int i = blockIdx.x * blockDim.x + threadIdx.x;
    if (i >= N_NODES * DIM) return;
    int n = i >> 7, d = i & 127;
    float v = node_emb[atom_type[n] * DIM + d];
    h0[i] = v;
    hb0[i] = f2bf(v);
}

// ---------------- CSR build (hierarchical scan — parallel; the single-block
// variant measured 106 us vs ~15 us for this chain) ----------------

__global__ void k_hist(const int* __restrict__ dst, int* __restrict__ counts) {
    int e = blockIdx.x * blockDim.x + threadIdx.x;
    if (e >= N_EDGES) return;
    atomicAdd(&counts[dst[e]], 1);
}

__global__ void k_bsum(const int* __restrict__ counts, int* __restrict__ bsums) {
    __shared__ int red[256];
    int c = blockIdx.x, tid = threadIdx.x;
    int base = c * CHUNK;
    int v = 0;
    for (int i = tid; i < CHUNK; i += 256)
        if (base + i < N_NODES) v += counts[base + i];
    red[tid] = v;
    __syncthreads();
    for (int s = 128; s > 0; s >>= 1) {
        if (tid < s) red[tid] += red[tid + s];
        __syncthreads();
    }
    if (tid == 0) bsums[c] = red[0];
}

__global__ void k_scan_b(int* __restrict__ bsums) {
    __shared__ int sb[NCHUNK];
    int tid = threadIdx.x;
    if (tid < NCHUNK) sb[tid] = bsums[tid];
    __syncthreads();
    if (tid == 0) {
        int run = 0;
        for (int i = 0; i < NCHUNK; ++i) { int v = sb[i]; sb[i] = run; run += v; }
    }
    __syncthreads();
    if (tid < NCHUNK) bsums[tid] = sb[tid];
}

__global__ void k_scan_final(const int* __restrict__ counts, const int* __restrict__ bsums,
                             int* __restrict__ offsets) {
    __shared__ int sc[CHUNK];
    int c = blockIdx.x, tid = threadIdx.x;
    int base = c * CHUNK;
    for (int i = tid; i < CHUNK; i += 256)
        sc[i] = (base + i < N_NODES) ? counts[base + i] : 0;
    __syncthreads();
    if (tid == 0) {
        int run = bsums[c];
        for (int i = 0; i < CHUNK; ++i) { int v = sc[i]; sc[i] = run; run += v; }
    }
    __syncthreads();
    for (int i = tid; i < CHUNK; i += 256)
        if (base + i < N_NODES) offsets[base + i] = sc[i];
    if (c == 0 && tid == 0) offsets[N_NODES] = N_EDGES;
}

// Fill perm-ordered meta: one uint2 per edge = (src, bin<<16 | w_fixed16).
__global__ void k_fill(const int* __restrict__ src, const int* __restrict__ dst,
                       const float* __restrict__ dist,
                       const int* __restrict__ offsets, int* __restrict__ cnt2,
                       uint2* __restrict__ meta) {
    int e = blockIdx.x * blockDim.x + threadIdx.x;
    if (e >= N_EDGES) return;
    int d = dst[e];
    int pos = offsets[d] + atomicAdd(&cnt2[d], 1);
    float x = dist[e];
    float p = x * ((float)NBINS / 10.0f);
    int bin = (int)p;
    if (bin > NBINS - 1) bin = NBINS - 1;
    float w = p - (float)bin;
    int wq = (int)(w * 65535.0f + 0.5f);
    if (wq > 65535) wq = 65535;
    meta[pos] = make_uint2((unsigned)src[e], ((unsigned)bin << 16) | (unsigned)wq);
}

// ---------------- tables (all layers upfront; depend only on weights) ----------------

__global__ void k_table_all(const float* __restrict__ Wc1, const float* __restrict__ bc1,
                            const float* __restrict__ Wc2, const float* __restrict__ bc2,
                            const float* __restrict__ Wc3, const float* __restrict__ bc3,
                            unsigned short* __restrict__ tableb) {
    __shared__ float t[DIM];
    __shared__ float u[DIM];
    int lyr = blockIdx.x / (NBINS + 1);
    int b = blockIdx.x % (NBINS + 1);
    int d = threadIdx.x;
    const float* wc1 = Wc1 + (size_t)lyr * RBF_R * DIM;
    const float* wc2 = Wc2 + (size_t)lyr * DIM * DIM;
    const float* wc3 = Wc3 + (size_t)lyr * DIM * DIM;
    float dist = (float)b * (10.0f / (float)NBINS);
    const float gap = 10.0f / 29.0f;
    float acc = bc1[lyr * DIM + d];
#pragma unroll
    for (int k = 0; k < RBF_R; ++k) {
        float c = (float)k * (10.0f / 29.0f);
        float df = dist - c;
        acc += expf(-df * df / gap) * wc1[k * DIM + d];
    }
    t[d] = sp05(acc);
    __syncthreads();
    acc = bc2[lyr * DIM + d];
#pragma unroll 8
    for (int k = 0; k < DIM; ++k) acc += t[k] * wc2[k * DIM + d];
    u[d] = acc;
    __syncthreads();
    acc = bc3[lyr * DIM + d];
#pragma unroll 8
    for (int k = 0; k < DIM; ++k) acc += u[k] * wc3[k * DIM + d];
    tableb[((size_t)lyr * (NBINS + 1) + b) * DIM + d] = f2bf(acc);
}

// Pack (a, delta) for all 3 layers: packed[lyr][bin][dim].
__global__ void k_pack_all(const unsigned short* __restrict__ tableb,
                           unsigned int* __restrict__ packed) {
    int i = blockIdx.x * 256 + threadIdx.x;   // 3*NBINS*128
    int lyr = i / (NBINS * DIM);
    int r = i % (NBINS * DIM);
    const unsigned short* tb = tableb + (size_t)lyr * (NBINS + 1) * DIM;
    float a = bf2f(tb[r]);
    float b = bf2f(tb[r + DIM]);
    packed[i] = (unsigned int)f2bf(a) | ((unsigned int)f2bf(b - a) << 16);
}

// ---------------- per-layer kernels ----------------

// MFMA GEMM: Cb = bf16( Ab @ W^T + bias + 1 ). Fragment-order B.
__global__ __launch_bounds__(256) void k_gemm_g(const unsigned short* __restrict__ Ab,
                                                const unsigned short* __restrict__ WtF,
                                                const float* __restrict__ bias,
                                                unsigned short* __restrict__ Cb) {
    int tid = threadIdx.x;
    int wave = tid >> 6, lane = tid & 63;
    int q = lane >> 4, l16 = lane & 15;
    int mhalf = wave & 1, nhalf = wave >> 1;
    int rb = blockIdx.x * 64 + mhalf * 32;
    int c0 = nhalf * 64;
    bf16x8 bfrag[4][4];
#pragma unroll
    for (int ks = 0; ks < 4; ++ks)
#pragma unroll
        for (int nt = 0; nt < 4; ++nt)
            bfrag[ks][nt] = *(const bf16x8*)&WtF[(size_t)(ks * 8 + nhalf * 4 + nt) * 512 + lane * 8];
    f32x4 acc[2][4] = {};
#pragma unroll
    for (int ks = 0; ks < 4; ++ks)
#pragma unroll
        for (int mt = 0; mt < 2; ++mt) {
            int m = rb + mt * 16 + l16;
            if (m > N_NODES - 1) m = N_NODES - 1;
            bf16x8 a = *(const bf16x8*)&Ab[(size_t)m * 128 + ks * 32 + q * 8];
#pragma unroll
            for (int nt = 0; nt < 4; ++nt)
                acc[mt][nt] = __builtin_amdgcn_mfma_f32_16x16x32_bf16(a, bfrag[ks][nt], acc[mt][nt], 0, 0, 0);
        }
#pragma unroll
    for (int mt = 0; mt < 2; ++mt)
#pragma unroll
        for (int nt = 0; nt < 4; ++nt) {
            int col = c0 + nt * 16 + l16;
            float b = bias[col] + 1.0f;
#pragma unroll
            for (int r = 0; r < 4; ++r) {
                int row = rb + mt * 16 + q * 4 + r;
                if (row < N_NODES) Cb[(size_t)row * 128 + col] = f2bf(acc[mt][nt][r] + b);
            }
        }
}

// Gather: wave-per-node (4 nodes / 256-block). Lane owns dims {2*lane, 2*lane+1}.
__global__ __launch_bounds__(256) void k_gather(
    const int* __restrict__ offsets, const uint2* __restrict__ meta,
    const unsigned int* __restrict__ packed, const unsigned short* __restrict__ gb,
    unsigned short* __restrict__ nodeb) {
    int wave = threadIdx.x >> 6, lane = threadIdx.x & 63;
    int n = blockIdx.x * 4 + wave;
    int beg = offsets[n], end = offsets[n + 1];
    int off = lane * 2;
    const float ws = 1.0f / 65535.0f;
    float acc0 = 0.f, acc1 = 0.f, acc2 = 0.f, acc3 = 0.f;
    int j = beg;
    for (; j + 4 <= end; j += 4) {
        uint2 m0 = meta[j], m1 = meta[j + 1], m2 = meta[j + 2], m3 = meta[j + 3];
        uint2 p0 = *(const uint2*)&packed[(size_t)(m0.y >> 16) * DIM + off];
        uint2 p1 = *(const uint2*)&packed[(size_t)(m1.y >> 16) * DIM + off];
        uint2 p2 = *(const uint2*)&packed[(size_t)(m2.y >> 16) * DIM + off];
        uint2 p3 = *(const uint2*)&packed[(size_t)(m3.y >> 16) * DIM + off];
        unsigned int g0 = *(const unsigned int*)&gb[(size_t)m0.x * DIM + off];
        unsigned int g1 = *(const unsigned int*)&gb[(size_t)m1.x * DIM + off];
        unsigned int g2 = *(const unsigned int*)&gb[(size_t)m2.x * DIM + off];
        unsigned int g3 = *(const unsigned int*)&gb[(size_t)m3.x * DIM + off];
        float w0 = (float)(m0.y & 0xffff) * ws;
        float w1 = (float)(m1.y & 0xffff) * ws;
        float w2 = (float)(m2.y & 0xffff) * ws;
        float w3 = (float)(m3.y & 0xffff) * ws;
        acc0 += bf2f(g0 & 0xffff) * (bf2f(p0.x & 0xffff) + w0 * bf2f(p0.x >> 16));
        acc1 += bf2f(g0 >> 16)    * (bf2f(p0.y & 0xffff) + w0 * bf2f(p0.y >> 16));
        acc2 += bf2f(g1 & 0xffff) * (bf2f(p1.x & 0xffff) + w1 * bf2f(p1.x >> 16));
        acc3 += bf2f(g1 >> 16)    * (bf2f(p1.y & 0xffff) + w1 * bf2f(p1.y >> 16));
        acc0 += bf2f(g2 & 0xffff) * (bf2f(p2.x & 0xffff) + w2 * bf2f(p2.x >> 16));
        acc1 += bf2f(g2 >> 16)    * (bf2f(p2.y & 0xffff) + w2 * bf2f(p2.y >> 16));
        acc2 += bf2f(g3 & 0xffff) * (bf2f(p3.x & 0xffff) + w3 * bf2f(p3.x >> 16));
        acc3 += bf2f(g3 >> 16)    * (bf2f(p3.y & 0xffff) + w3 * bf2f(p3.y >> 16));
    }
    for (; j < end; ++j) {
        uint2 m0 = meta[j];
        uint2 p0 = *(const uint2*)&packed[(size_t)(m0.y >> 16) * DIM + off];
        unsigned int g0 = *(const unsigned int*)&gb[(size_t)m0.x * DIM + off];
        float w0 = (float)(m0.y & 0xffff) * ws;
        acc0 += bf2f(g0 & 0xffff) * (bf2f(p0.x & 0xffff) + w0 * bf2f(p0.x >> 16));
        acc1 += bf2f(g0 >> 16)    * (bf2f(p0.y & 0xffff) + w0 * bf2f(p0.y >> 16));
    }
    acc0 += acc2; acc1 += acc3;
    unsigned int o = (unsigned int)f2bf(acc0) | ((unsigned int)f2bf(acc1) << 16);
    *(unsigned int*)&nodeb[(size_t)n * DIM + off] = o;
}

// h_out = h_in + sp05(nodeb@W2^T + b2) @ W3^T + b3 ; fp32 + bf16 outputs.
__global__ __launch_bounds__(256) void k_node_update(
    const unsigned short* __restrict__ nodeb,
    const unsigned short* __restrict__ W2tF, const float* __restrict__ b2,
    const unsigned short* __restrict__ W3tF, const float* __restrict__ b3,
    const float* __restrict__ h_in, float* __restrict__ h_out,
    unsigned short* __restrict__ hb_out) {
    __shared__ unsigned short ts[64][136];
    int tid = threadIdx.x;
    int wave = tid >> 6, lane = tid & 63;
    int q = lane >> 4, l16 = lane & 15;
    int mhalf = wave & 1, nhalf = wave >> 1;
    int rb = blockIdx.x * 64 + mhalf * 32;
    int c0 = nhalf * 64;

    bf16x8 bfrag[4][4];
#pragma unroll
    for (int ks = 0; ks < 4; ++ks)
#pragma unroll
        for (int nt = 0; nt < 4; ++nt)
            bfrag[ks][nt] = *(const bf16x8*)&W2tF[(size_t)(ks * 8 + nhalf * 4 + nt) * 512 + lane * 8];
    f32x4 acc[2][4] = {};
#pragma unroll
    for (int ks = 0; ks < 4; ++ks)
#pragma unroll
        for (int mt = 0; mt < 2; ++mt) {
            int m = rb + mt * 16 + l16;
            if (m > N_NODES - 1) m = N_NODES - 1;
            bf16x8 a = *(const bf16x8*)&nodeb[(size_t)m * 128 + ks * 32 + q * 8];
#pragma unroll
            for (int nt = 0; nt < 4; ++nt)
                acc[mt][nt] = __builtin_amdgcn_mfma_f32_16x16x32_bf16(a, bfrag[ks][nt], acc[mt][nt], 0, 0, 0);
        }
#pragma unroll
    for (int mt = 0; mt < 2; ++mt)
#pragma unroll
        for (int nt = 0; nt < 4; ++nt) {
            int col = c0 + nt * 16 + l16;
            float b = b2[col];
#pragma unroll
            for (int r = 0; r < 4; ++r) {
                int lrow = mhalf * 32 + mt * 16 + q * 4 + r;
                ts[lrow][col] = f2bf(sp05(acc[mt][nt][r] + b));
            }
        }
    __syncthreads();
#pragma unroll
    for (int ks = 0; ks < 4; ++ks)
#pragma unroll
        for (int nt = 0; nt < 4; ++nt)
            bfrag[ks][nt] = *(const bf16x8*)&W3tF[(size_t)(ks * 8 + nhalf * 4 + nt) * 512 + lane * 8];
#pragma unroll
    for (int mt = 0; mt < 2; ++mt)
#pragma unroll
        for (int nt = 0; nt < 4; ++nt) acc[mt][nt] = (f32x4){0.f, 0.f, 0.f, 0.f};
#pragma unroll
    for (int ks = 0; ks < 4; ++ks)
#pragma unroll
        for (int mt = 0; mt < 2; ++mt) {
            int lrow = mhalf * 32 + mt * 16 + l16;
            bf16x8 a = *(const bf16x8*)&ts[lrow][ks * 32 + q * 8];
#pragma unroll
            for (int nt = 0; nt < 4; ++nt)
                acc[mt][nt] = __builtin_amdgcn_mfma_f32_16x16x32_bf16(a, bfrag[ks][nt], acc[mt][nt], 0, 0, 0);
        }
#pragma unroll
    for (int mt = 0; mt < 2; ++mt)
#pragma unroll
        for (int nt = 0; nt < 4; ++nt) {
            int col = c0 + nt * 16 + l16;
            float b = b3[col];
#pragma unroll
            for (int r = 0; r < 4; ++r) {
                int row = rb + mt * 16 + q * 4 + r;
                if (row < N_NODES) {
                    size_t idx = (size_t)row * 128 + col;
                    float v = h_in[idx] + acc[mt][nt][r] + b;
                    h_out[idx] = v;
                    hb_out[idx] = f2bf(v);
                }
            }
        }
}

// Readout: round-5 best config — 128 rows/block (2 m-tiles/wave), global
// fragment-order B loads, no LDS. Measured 75 us; LDS staging (r7) and
// 64-row blocks (r6) both regressed.
__global__ __launch_bounds__(256) void k_readout(
    const unsigned short* __restrict__ hb0, const unsigned short* __restrict__ hb1,
    const unsigned short* __restrict__ hb2, const unsigned short* __restrict__ hb3,
    const unsigned short* __restrict__ Wr1tF, const float* __restrict__ br1,
    const float* __restrict__ Wr2, const float* __restrict__ br2,
    const int* __restrict__ graph_ids, float* __restrict__ out) {
    int tid = threadIdx.x;
    int wave = tid >> 6, lane = tid & 63;
    int q = lane >> 4, l16 = lane & 15;
    int rb0 = blockIdx.x * 128 + wave * 16;   // m-tile mt at rb0 + mt*64
    const unsigned short* hbs[4] = {hb0, hb1, hb2, hb3};
    f32x4 acc[2][4] = {};
    for (int lvl = 0; lvl < 4; ++lvl) {
        bf16x8 bfrag[4][4];
#pragma unroll
        for (int ks = 0; ks < 4; ++ks)
#pragma unroll
            for (int nt = 0; nt < 4; ++nt)
                bfrag[ks][nt] = *(const bf16x8*)&Wr1tF[(size_t)((lvl * 4 + ks) * 4 + nt) * 512 + lane * 8];
        const unsigned short* Ab = hbs[lvl];
#pragma unroll
        for (int ks = 0; ks < 4; ++ks)
#pragma unroll
            for (int mt = 0; mt < 2; ++mt) {
                int m = rb0 + mt * 64 + l16;
                if (m > N_NODES - 1) m = N_NODES - 1;
                bf16x8 a = *(const bf16x8*)&Ab[(size_t)m * 128 + ks * 32 + q * 8];
#pragma unroll
                for (int nt = 0; nt < 4; ++nt)
                    acc[mt][nt] = __builtin_amdgcn_mfma_f32_16x16x32_bf16(a, bfrag[ks][nt], acc[mt][nt], 0, 0, 0);
            }
    }
    float brr = br2[0];
#pragma unroll
    for (int mt = 0; mt < 2; ++mt) {
        float partial[4] = {0.f, 0.f, 0.f, 0.f};
#pragma unroll
        for (int nt = 0; nt < 4; ++nt) {
            int col = nt * 16 + l16;
            float b = br1[col];
            float w = Wr2[col];
#pragma unroll
            for (int r = 0; r < 4; ++r) partial[r] += sp1(acc[mt][nt][r] + b) * w;
        }
#pragma unroll
        for (int r = 0; r < 4; ++r) {
            float v = partial[r];
            v += __shfl_xor(v, 1); v += __shfl_xor(v, 2);
            v += __shfl_xor(v, 4); v += __shfl_xor(v, 8);
            if (l16 == 0) {
                int row = rb0 + mt * 64 + q * 4 + r;
                if (row < N_NODES) atomicAdd(&out[graph_ids[row]], v + brr);
            }
        }
    }
}

extern "C" void kernel_launch(void* const* d_in, const int* in_sizes, int n_in,
                              void* d_out, int out_size, void* d_ws, size_t ws_size,
                              hipStream_t stream) {
    const int* atom_type   = (const int*)d_in[0];
    const int* src         = (const int*)d_in[1];
    const int* dst         = (const int*)d_in[2];
    const int* graph_ids   = (const int*)d_in[3];
    const float* dist      = (const float*)d_in[4];
    const float* node_emb  = (const float*)d_in[5];
    const float* W_n1 = (const float*)d_in[6];  const float* b_n1 = (const float*)d_in[7];
    const float* W_c1 = (const float*)d_in[8];  const float* b_c1 = (const float*)d_in[9];
    const float* W_c2 = (const float*)d_in[10]; const float* b_c2 = (const float*)d_in[11];
    const float* W_c3 = (const float*)d_in[12]; const float* b_c3 = (const float*)d_in[13];
    const float* W_n2 = (const float*)d_in[14]; const float* b_n2 = (const float*)d_in[15];
    const float* W_n3 = (const float*)d_in[16]; const float* b_n3 = (const float*)d_in[17];
    const float* W_r1 = (const float*)d_in[18]; const float* b_r1 = (const float*)d_in[19];
    const float* W_r2 = (const float*)d_in[20]; const float* b_r2 = (const float*)d_in[21];
    float* out = (float*)d_out;

    size_t ND = (size_t)N_NODES * DIM;   // 7,680,000
    // float region
    float* h_even = (float*)d_ws;
    float* h_odd  = h_even + ND;
    // uint2 meta (8-B aligned)
    uint2* meta   = (uint2*)(h_odd + ND);               // N_EDGES
    // int region
    int* offsets  = (int*)(meta + N_EDGES);             // 60008 (padded)
    int* counts   = offsets + 60008;                    // 60000
    int* cnt2     = counts + N_NODES;                   // 60000
    int* bsums    = cnt2 + N_NODES;                     // 128 (padded)
    unsigned int* packed = (unsigned int*)(bsums + 128);  // 3*NBINS*128
    // ushort region
    unsigned short* hb0    = (unsigned short*)(packed + (size_t)3 * NBINS * DIM);
    unsigned short* hb1    = hb0 + ND;
    unsigned short* hb2    = hb1 + ND;
    unsigned short* hb3    = hb2 + ND;
    unsigned short* gb     = hb3 + ND;
    unsigned short* nodeb  = gb + ND;
    unsigned short* tableb = nodeb + ND;                // 3*(NBINS+1)*128
    unsigned short* WtF    = tableb + (size_t)3 * (NBINS + 1) * DIM;  // 9*16384
    unsigned short* Wr1tF  = WtF + 9 * 16384;           // 32768

    unsigned short* hbp[4] = {hb0, hb1, hb2, hb3};
    float* hcur = h_even;
    float* hnext = h_odd;

    hipMemsetAsync(out, 0, B_GRAPHS * sizeof(float), stream);
    hipMemsetAsync(counts, 0, (2 * N_NODES + 128) * sizeof(int), stream);

    // one-time setup (all before the layer loop; tables depend only on weights)
    k_conv<<<(9 * 16384 + 32768 + 255) / 256, 256, 0, stream>>>(
        W_n1, W_n2, W_n3, W_r1, WtF, Wr1tF);
    k_embed<<<(N_NODES * DIM) / 256, 256, 0, stream>>>(atom_type, node_emb, h_even, hb0);
    k_table_all<<<3 * (NBINS + 1), DIM, 0, stream>>>(
        W_c1, b_c1, W_c2, b_c2, W_c3, b_c3, tableb);
    k_pack_all<<<(3 * NBINS * DIM) / 256, 256, 0, stream>>>(tableb, packed);

    // CSR build (dst-sorted edge meta)
    k_hist<<<(N_EDGES + 255) / 256, 256, 0, stream>>>(dst, counts);
    k_bsum<<<NCHUNK, 256, 0, stream>>>(counts, bsums);
    k_scan_b<<<1, 128, 0, stream>>>(bsums);
    k_scan_final<<<NCHUNK, 256, 0, stream>>>(counts, bsums, offsets);
    k_fill<<<(N_EDGES + 255) / 256, 256, 0, stream>>>(src, dst, dist, offsets, cnt2, meta);

    int gblocks = (N_NODES + 63) / 64;      // 938
    int rblocks = (N_NODES + 127) / 128;    // 469
    for (int i = 0; i < NLAYERS; ++i) {
        k_gemm_g<<<gblocks, 256, 0, stream>>>(
            hbp[i], WtF + (size_t)i * 16384, b_n1 + (size_t)i * DIM, gb);
        k_gather<<<N_NODES / 4, 256, 0, stream>>>(
            offsets, meta, packed + (size_t)i * NBINS * DIM, gb, nodeb);
        k_node_update<<<gblocks, 256, 0, stream>>>(
            nodeb, WtF + (size_t)(3 + i) * 16384, b_n2 + (size_t)i * DIM,
            WtF + (size_t)(6 + i) * 16384, b_n3 + (size_t)i * DIM,
            hcur, hnext, hbp[i + 1]);
        float* tmp = hcur; hcur = hnext; hnext = tmp;
    }
    k_readout<<<rblocks, 256, 0, stream>>>(
        hb0, hb1, hb2, hb3, Wr1tF, b_r1, W_r2, b_r2, graph_ids, out);
}

// Round 10
// 569.066 us; speedup vs baseline: 1.1938x; 1.0308x over previous
//
#include <hip/hip_runtime.h>
#include <math.h>

#define N_NODES 60000
#define N_EDGES 600000
#define B_GRAPHS 512
#define DIM 128
#define RBF_R 30
#define NLAYERS 3
#define NBINS 1024
#define CHUNK 512
#define NCHUNK ((N_NODES + CHUNK - 1) / CHUNK)   // 118

typedef __attribute__((ext_vector_type(8))) short bf16x8;
typedef __attribute__((ext_vector_type(4))) float f32x4;

__device__ __forceinline__ float sp05(float x) {
    float bx = 0.5f * x;
    return bx > 14.0f ? x : 2.0f * log1pf(expf(bx));
}
__device__ __forceinline__ float sp1(float x) {
    return x > 20.0f ? x : log1pf(expf(x));
}
__device__ __forceinline__ unsigned short f2bf(float f) {
    unsigned int u = __float_as_uint(f);
    unsigned int r = u + 0x7FFFu + ((u >> 16) & 1u);  // RNE
    return (unsigned short)(r >> 16);
}
__device__ __forceinline__ float bf2f(unsigned int s) {
    return __uint_as_float(s << 16);
}

// ---------------- one-time conversion (fused) ----------------
// Fragment-order: each MFMA B-fragment (64 lanes x 16B) stored contiguously.
__global__ void k_conv(const float* __restrict__ Wn1, const float* __restrict__ Wn2,
                       const float* __restrict__ Wn3, const float* __restrict__ Wr1,
                       unsigned short* __restrict__ WtF, unsigned short* __restrict__ Wr1tF) {
    int i = blockIdx.x * 256 + threadIdx.x;
    if (i < 9 * 16384) {
        int mat = i >> 14, r = i & 16383;
        int frag = r >> 9, within = r & 511;
        int ks = frag >> 3, ntile = frag & 7;
        int lane = within >> 3, j = within & 7;
        int q = lane >> 4, l16 = lane & 15;
        int n = ntile * 16 + l16;
        int k = ks * 32 + q * 8 + j;
        const float* src = (mat < 3) ? (Wn1 + (size_t)mat * 16384)
                         : (mat < 6) ? (Wn2 + (size_t)(mat - 3) * 16384)
                                     : (Wn3 + (size_t)(mat - 6) * 16384);
        WtF[i] = f2bf(src[k * 128 + n]);
    } else {
        int ii = i - 9 * 16384;
        if (ii < 32768) {
            int frag = ii >> 9, within = ii & 511;
            int lvl = frag >> 4, ks = (frag >> 2) & 3, ntile = frag & 3;
            int lane = within >> 3, j = within & 7;
            int q = lane >> 4, l16 = lane & 15;
            int n = ntile * 16 + l16;
            int k = lvl * 128 + ks * 32 + q * 8 + j;
            Wr1tF[ii] = f2bf(Wr1[k * 64 + n]);
        }
    }
}

// hb0 = bf16(node_emb[atom_type])   (h lives only in bf16 now)
__global__ void k_embed(const int* __restrict__ atom_type,
                        const float* __restrict__ node_emb,
                        unsigned short* __restrict__ hb0) {
    int i = blockIdx.x * blockDim.x + threadIdx.x;
    if (i >= N_NODES * DIM) return;
    int n = i >> 7, d = i & 127;
    hb0[i] = f2bf(node_emb[atom_type[n] * DIM + d]);
}

// ---------------- CSR build (hierarchical scan) ----------------

__global__ void k_hist(const int* __restrict__ dst, int* __restrict__ counts) {
    int e = blockIdx.x * blockDim.x + threadIdx.x;
    if (e >= N_EDGES) return;
    atomicAdd(&counts[dst[e]], 1);
}

__global__ void k_bsum(const int* __restrict__ counts, int* __restrict__ bsums) {
    __shared__ int red[256];
    int c = blockIdx.x, tid = threadIdx.x;
    int base = c * CHUNK;
    int v = 0;
    for (int i = tid; i < CHUNK; i += 256)
        if (base + i < N_NODES) v += counts[base + i];
    red[tid] = v;
    __syncthreads();
    for (int s = 128; s > 0; s >>= 1) {
        if (tid < s) red[tid] += red[tid + s];
        __syncthreads();
    }
    if (tid == 0) bsums[c] = red[0];
}

__global__ void k_scan_b(int* __restrict__ bsums) {
    __shared__ int sb[NCHUNK];
    int tid = threadIdx.x;
    if (tid < NCHUNK) sb[tid] = bsums[tid];
    __syncthreads();
    if (tid == 0) {
        int run = 0;
        for (int i = 0; i < NCHUNK; ++i) { int v = sb[i]; sb[i] = run; run += v; }
    }
    __syncthreads();
    if (tid < NCHUNK) bsums[tid] = sb[tid];
}

__global__ void k_scan_final(const int* __restrict__ counts, const int* __restrict__ bsums,
                             int* __restrict__ offsets) {
    __shared__ int sc[CHUNK];
    int c = blockIdx.x, tid = threadIdx.x;
    int base = c * CHUNK;
    for (int i = tid; i < CHUNK; i += 256)
        sc[i] = (base + i < N_NODES) ? counts[base + i] : 0;
    __syncthreads();
    if (tid == 0) {
        int run = bsums[c];
        for (int i = 0; i < CHUNK; ++i) { int v = sc[i]; sc[i] = run; run += v; }
    }
    __syncthreads();
    for (int i = tid; i < CHUNK; i += 256)
        if (base + i < N_NODES) offsets[base + i] = sc[i];
    if (c == 0 && tid == 0) offsets[N_NODES] = N_EDGES;
}

// Fill perm-ordered meta: one uint2 per edge = (src, bin<<16 | w_fixed16).
__global__ void k_fill(const int* __restrict__ src, const int* __restrict__ dst,
                       const float* __restrict__ dist,
                       const int* __restrict__ offsets, int* __restrict__ cnt2,
                       uint2* __restrict__ meta) {
    int e = blockIdx.x * blockDim.x + threadIdx.x;
    if (e >= N_EDGES) return;
    int d = dst[e];
    int pos = offsets[d] + atomicAdd(&cnt2[d], 1);
    float x = dist[e];
    float p = x * ((float)NBINS / 10.0f);
    int bin = (int)p;
    if (bin > NBINS - 1) bin = NBINS - 1;
    float w = p - (float)bin;
    int wq = (int)(w * 65535.0f + 0.5f);
    if (wq > 65535) wq = 65535;
    meta[pos] = make_uint2((unsigned)src[e], ((unsigned)bin << 16) | (unsigned)wq);
}

// ---------------- tables (all layers upfront; depend only on weights) ----------------

__global__ void k_table_all(const float* __restrict__ Wc1, const float* __restrict__ bc1,
                            const float* __restrict__ Wc2, const float* __restrict__ bc2,
                            const float* __restrict__ Wc3, const float* __restrict__ bc3,
                            unsigned short* __restrict__ tableb) {
    __shared__ float t[DIM];
    __shared__ float u[DIM];
    int lyr = blockIdx.x / (NBINS + 1);
    int b = blockIdx.x % (NBINS + 1);
    int d = threadIdx.x;
    const float* wc1 = Wc1 + (size_t)lyr * RBF_R * DIM;
    const float* wc2 = Wc2 + (size_t)lyr * DIM * DIM;
    const float* wc3 = Wc3 + (size_t)lyr * DIM * DIM;
    float dist = (float)b * (10.0f / (float)NBINS);
    const float gap = 10.0f / 29.0f;
    float acc = bc1[lyr * DIM + d];
#pragma unroll
    for (int k = 0; k < RBF_R; ++k) {
        float c = (float)k * (10.0f / 29.0f);
        float df = dist - c;
        acc += expf(-df * df / gap) * wc1[k * DIM + d];
    }
    t[d] = sp05(acc);
    __syncthreads();
    acc = bc2[lyr * DIM + d];
#pragma unroll 8
    for (int k = 0; k < DIM; ++k) acc += t[k] * wc2[k * DIM + d];
    u[d] = acc;
    __syncthreads();
    acc = bc3[lyr * DIM + d];
#pragma unroll 8
    for (int k = 0; k < DIM; ++k) acc += u[k] * wc3[k * DIM + d];
    tableb[((size_t)lyr * (NBINS + 1) + b) * DIM + d] = f2bf(acc);
}

// Pack (a, delta) for all 3 layers: packed[lyr][bin][dim].
__global__ void k_pack_all(const unsigned short* __restrict__ tableb,
                           unsigned int* __restrict__ packed) {
    int i = blockIdx.x * 256 + threadIdx.x;   // 3*NBINS*128
    int lyr = i / (NBINS * DIM);
    int r = i % (NBINS * DIM);
    const unsigned short* tb = tableb + (size_t)lyr * (NBINS + 1) * DIM;
    float a = bf2f(tb[r]);
    float b = bf2f(tb[r + DIM]);
    packed[i] = (unsigned int)f2bf(a) | ((unsigned int)f2bf(b - a) << 16);
}

// ---------------- per-layer kernels ----------------

// MFMA GEMM (layer 0 only): gb = bf16( hb0 @ Wn1_0^T + b + 1 ).
__global__ __launch_bounds__(256) void k_gemm_g(const unsigned short* __restrict__ Ab,
                                                const unsigned short* __restrict__ WtF,
                                                const float* __restrict__ bias,
                                                unsigned short* __restrict__ Cb) {
    int tid = threadIdx.x;
    int wave = tid >> 6, lane = tid & 63;
    int q = lane >> 4, l16 = lane & 15;
    int mhalf = wave & 1, nhalf = wave >> 1;
    int rb = blockIdx.x * 64 + mhalf * 32;
    int c0 = nhalf * 64;
    bf16x8 bfrag[4][4];
#pragma unroll
    for (int ks = 0; ks < 4; ++ks)
#pragma unroll
        for (int nt = 0; nt < 4; ++nt)
            bfrag[ks][nt] = *(const bf16x8*)&WtF[(size_t)(ks * 8 + nhalf * 4 + nt) * 512 + lane * 8];
    f32x4 acc[2][4] = {};
#pragma unroll
    for (int ks = 0; ks < 4; ++ks)
#pragma unroll
        for (int mt = 0; mt < 2; ++mt) {
            int m = rb + mt * 16 + l16;
            if (m > N_NODES - 1) m = N_NODES - 1;
            bf16x8 a = *(const bf16x8*)&Ab[(size_t)m * 128 + ks * 32 + q * 8];
#pragma unroll
            for (int nt = 0; nt < 4; ++nt)
                acc[mt][nt] = __builtin_amdgcn_mfma_f32_16x16x32_bf16(a, bfrag[ks][nt], acc[mt][nt], 0, 0, 0);
        }
#pragma unroll
    for (int mt = 0; mt < 2; ++mt)
#pragma unroll
        for (int nt = 0; nt < 4; ++nt) {
            int col = c0 + nt * 16 + l16;
            float b = bias[col] + 1.0f;
#pragma unroll
            for (int r = 0; r < 4; ++r) {
                int row = rb + mt * 16 + q * 4 + r;
                if (row < N_NODES) Cb[(size_t)row * 128 + col] = f2bf(acc[mt][nt][r] + b);
            }
        }
}

// Gather: wave-per-node (4 nodes / 256-block). Lane owns dims {2*lane, 2*lane+1}.
__global__ __launch_bounds__(256) void k_gather(
    const int* __restrict__ offsets, const uint2* __restrict__ meta,
    const unsigned int* __restrict__ packed, const unsigned short* __restrict__ gb,
    unsigned short* __restrict__ nodeb) {
    int wave = threadIdx.x >> 6, lane = threadIdx.x & 63;
    int n = blockIdx.x * 4 + wave;
    int beg = offsets[n], end = offsets[n + 1];
    int off = lane * 2;
    const float ws = 1.0f / 65535.0f;
    float acc0 = 0.f, acc1 = 0.f, acc2 = 0.f, acc3 = 0.f;
    int j = beg;
    for (; j + 4 <= end; j += 4) {
        uint2 m0 = meta[j], m1 = meta[j + 1], m2 = meta[j + 2], m3 = meta[j + 3];
        uint2 p0 = *(const uint2*)&packed[(size_t)(m0.y >> 16) * DIM + off];
        uint2 p1 = *(const uint2*)&packed[(size_t)(m1.y >> 16) * DIM + off];
        uint2 p2 = *(const uint2*)&packed[(size_t)(m2.y >> 16) * DIM + off];
        uint2 p3 = *(const uint2*)&packed[(size_t)(m3.y >> 16) * DIM + off];
        unsigned int g0 = *(const unsigned int*)&gb[(size_t)m0.x * DIM + off];
        unsigned int g1 = *(const unsigned int*)&gb[(size_t)m1.x * DIM + off];
        unsigned int g2 = *(const unsigned int*)&gb[(size_t)m2.x * DIM + off];
        unsigned int g3 = *(const unsigned int*)&gb[(size_t)m3.x * DIM + off];
        float w0 = (float)(m0.y & 0xffff) * ws;
        float w1 = (float)(m1.y & 0xffff) * ws;
        float w2 = (float)(m2.y & 0xffff) * ws;
        float w3 = (float)(m3.y & 0xffff) * ws;
        acc0 += bf2f(g0 & 0xffff) * (bf2f(p0.x & 0xffff) + w0 * bf2f(p0.x >> 16));
        acc1 += bf2f(g0 >> 16)    * (bf2f(p0.y & 0xffff) + w0 * bf2f(p0.y >> 16));
        acc2 += bf2f(g1 & 0xffff) * (bf2f(p1.x & 0xffff) + w1 * bf2f(p1.x >> 16));
        acc3 += bf2f(g1 >> 16)    * (bf2f(p1.y & 0xffff) + w1 * bf2f(p1.y >> 16));
        acc0 += bf2f(g2 & 0xffff) * (bf2f(p2.x & 0xffff) + w2 * bf2f(p2.x >> 16));
        acc1 += bf2f(g2 >> 16)    * (bf2f(p2.y & 0xffff) + w2 * bf2f(p2.y >> 16));
        acc2 += bf2f(g3 & 0xffff) * (bf2f(p3.x & 0xffff) + w3 * bf2f(p3.x >> 16));
        acc3 += bf2f(g3 >> 16)    * (bf2f(p3.y & 0xffff) + w3 * bf2f(p3.y >> 16));
    }
    for (; j < end; ++j) {
        uint2 m0 = meta[j];
        uint2 p0 = *(const uint2*)&packed[(size_t)(m0.y >> 16) * DIM + off];
        unsigned int g0 = *(const unsigned int*)&gb[(size_t)m0.x * DIM + off];
        float w0 = (float)(m0.y & 0xffff) * ws;
        acc0 += bf2f(g0 & 0xffff) * (bf2f(p0.x & 0xffff) + w0 * bf2f(p0.x >> 16));
        acc1 += bf2f(g0 >> 16)    * (bf2f(p0.y & 0xffff) + w0 * bf2f(p0.y >> 16));
    }
    acc0 += acc2; acc1 += acc3;
    unsigned int o = (unsigned int)f2bf(acc0) | ((unsigned int)f2bf(acc1) << 16);
    *(unsigned int*)&nodeb[(size_t)n * DIM + off] = o;
}

// Fused node update (+ next layer's g):
//   h_out = hb_in + sp05(nodeb@W2^T + b2) @ W3^T + b3      (bf16 residual stream)
//   if do_g: gb = bf16( h_out @ Wg^T + bg + 1 )            (next layer's g)
__global__ __launch_bounds__(256) void k_node_update(
    const unsigned short* __restrict__ nodeb,
    const unsigned short* __restrict__ W2tF, const float* __restrict__ b2,
    const unsigned short* __restrict__ W3tF, const float* __restrict__ b3,
    const unsigned short* __restrict__ hb_in, unsigned short* __restrict__ hb_out,
    const unsigned short* __restrict__ WgF, const float* __restrict__ bg,
    unsigned short* __restrict__ gb, int do_g) {
    __shared__ unsigned short ts[64][136];
    __shared__ unsigned short hs[64][136];
    int tid = threadIdx.x;
    int wave = tid >> 6, lane = tid & 63;
    int q = lane >> 4, l16 = lane & 15;
    int mhalf = wave & 1, nhalf = wave >> 1;
    int rb = blockIdx.x * 64 + mhalf * 32;
    int c0 = nhalf * 64;

    bf16x8 bfrag[4][4];
#pragma unroll
    for (int ks = 0; ks < 4; ++ks)
#pragma unroll
        for (int nt = 0; nt < 4; ++nt)
            bfrag[ks][nt] = *(const bf16x8*)&W2tF[(size_t)(ks * 8 + nhalf * 4 + nt) * 512 + lane * 8];
    f32x4 acc[2][4] = {};
#pragma unroll
    for (int ks = 0; ks < 4; ++ks)
#pragma unroll
        for (int mt = 0; mt < 2; ++mt) {
            int m = rb + mt * 16 + l16;
            if (m > N_NODES - 1) m = N_NODES - 1;
            bf16x8 a = *(const bf16x8*)&nodeb[(size_t)m * 128 + ks * 32 + q * 8];
#pragma unroll
            for (int nt = 0; nt < 4; ++nt)
                acc[mt][nt] = __builtin_amdgcn_mfma_f32_16x16x32_bf16(a, bfrag[ks][nt], acc[mt][nt], 0, 0, 0);
        }
#pragma unroll
    for (int mt = 0; mt < 2; ++mt)
#pragma unroll
        for (int nt = 0; nt < 4; ++nt) {
            int col = c0 + nt * 16 + l16;
            float b = b2[col];
#pragma unroll
            for (int r = 0; r < 4; ++r) {
                int lrow = mhalf * 32 + mt * 16 + q * 4 + r;
                ts[lrow][col] = f2bf(sp05(acc[mt][nt][r] + b));
            }
        }
    __syncthreads();
#pragma unroll
    for (int ks = 0; ks < 4; ++ks)
#pragma unroll
        for (int nt = 0; nt < 4; ++nt)
            bfrag[ks][nt] = *(const bf16x8*)&W3tF[(size_t)(ks * 8 + nhalf * 4 + nt) * 512 + lane * 8];
#pragma unroll
    for (int mt = 0; mt < 2; ++mt)
#pragma unroll
        for (int nt = 0; nt < 4; ++nt) acc[mt][nt] = (f32x4){0.f, 0.f, 0.f, 0.f};
#pragma unroll
    for (int ks = 0; ks < 4; ++ks)
#pragma unroll
        for (int mt = 0; mt < 2; ++mt) {
            int lrow = mhalf * 32 + mt * 16 + l16;
            bf16x8 a = *(const bf16x8*)&ts[lrow][ks * 32 + q * 8];
#pragma unroll
            for (int nt = 0; nt < 4; ++nt)
                acc[mt][nt] = __builtin_amdgcn_mfma_f32_16x16x32_bf16(a, bfrag[ks][nt], acc[mt][nt], 0, 0, 0);
        }
    // h_out = hb_in + acc + b3 ; store bf16 + stage into hs (A-layout source form)
#pragma unroll
    for (int mt = 0; mt < 2; ++mt)
#pragma unroll
        for (int nt = 0; nt < 4; ++nt) {
            int col = c0 + nt * 16 + l16;
            float b = b3[col];
#pragma unroll
            for (int r = 0; r < 4; ++r) {
                int row = rb + mt * 16 + q * 4 + r;
                int lrow = mhalf * 32 + mt * 16 + q * 4 + r;
                size_t idx = (size_t)row * 128 + col;
                float v;
                if (row < N_NODES) {
                    v = bf2f(hb_in[idx]) + acc[mt][nt][r] + b;
                    unsigned short bf = f2bf(v);
                    hb_out[idx] = bf;
                    hs[lrow][col] = bf;
                } else {
                    hs[lrow][col] = 0;
                }
            }
        }
    if (!do_g) return;
    __syncthreads();
    // third GEMM: gb = h_out @ Wg^T + bg + 1
#pragma unroll
    for (int ks = 0; ks < 4; ++ks)
#pragma unroll
        for (int nt = 0; nt < 4; ++nt)
            bfrag[ks][nt] = *(const bf16x8*)&WgF[(size_t)(ks * 8 + nhalf * 4 + nt) * 512 + lane * 8];
#pragma unroll
    for (int mt = 0; mt < 2; ++mt)
#pragma unroll
        for (int nt = 0; nt < 4; ++nt) acc[mt][nt] = (f32x4){0.f, 0.f, 0.f, 0.f};
#pragma unroll
    for (int ks = 0; ks < 4; ++ks)
#pragma unroll
        for (int mt = 0; mt < 2; ++mt) {
            int lrow = mhalf * 32 + mt * 16 + l16;
            bf16x8 a = *(const bf16x8*)&hs[lrow][ks * 32 + q * 8];
#pragma unroll
            for (int nt = 0; nt < 4; ++nt)
                acc[mt][nt] = __builtin_amdgcn_mfma_f32_16x16x32_bf16(a, bfrag[ks][nt], acc[mt][nt], 0, 0, 0);
        }
#pragma unroll
    for (int mt = 0; mt < 2; ++mt)
#pragma unroll
        for (int nt = 0; nt < 4; ++nt) {
            int col = c0 + nt * 16 + l16;
            float b = bg[col] + 1.0f;
#pragma unroll
            for (int r = 0; r < 4; ++r) {
                int row = rb + mt * 16 + q * 4 + r;
                if (row < N_NODES) gb[(size_t)row * 128 + col] = f2bf(acc[mt][nt][r] + b);
            }
        }
}

// Readout: round-5 best config — 128 rows/block (2 m-tiles/wave), global
// fragment-order B loads, no LDS. Measured 75 us; LDS staging (r7) and
// 64-row blocks (r6) both regressed.
__global__ __launch_bounds__(256) void k_readout(
    const unsigned short* __restrict__ hb0, const unsigned short* __restrict__ hb1,
    const unsigned short* __restrict__ hb2, const unsigned short* __restrict__ hb3,
    const unsigned short* __restrict__ Wr1tF, const float* __restrict__ br1,
    const float* __restrict__ Wr2, const float* __restrict__ br2,
    const int* __restrict__ graph_ids, float* __restrict__ out) {
    int tid = threadIdx.x;
    int wave = tid >> 6, lane = tid & 63;
    int q = lane >> 4, l16 = lane & 15;
    int rb0 = blockIdx.x * 128 + wave * 16;   // m-tile mt at rb0 + mt*64
    const unsigned short* hbs[4] = {hb0, hb1, hb2, hb3};
    f32x4 acc[2][4] = {};
    for (int lvl = 0; lvl < 4; ++lvl) {
        bf16x8 bfrag[4][4];
#pragma unroll
        for (int ks = 0; ks < 4; ++ks)
#pragma unroll
            for (int nt = 0; nt < 4; ++nt)
                bfrag[ks][nt] = *(const bf16x8*)&Wr1tF[(size_t)((lvl * 4 + ks) * 4 + nt) * 512 + lane * 8];
        const unsigned short* Ab = hbs[lvl];
#pragma unroll
        for (int ks = 0; ks < 4; ++ks)
#pragma unroll
            for (int mt = 0; mt < 2; ++mt) {
                int m = rb0 + mt * 64 + l16;
                if (m > N_NODES - 1) m = N_NODES - 1;
                bf16x8 a = *(const bf16x8*)&Ab[(size_t)m * 128 + ks * 32 + q * 8];
#pragma unroll
                for (int nt = 0; nt < 4; ++nt)
                    acc[mt][nt] = __builtin_amdgcn_mfma_f32_16x16x32_bf16(a, bfrag[ks][nt], acc[mt][nt], 0, 0, 0);
            }
    }
    float brr = br2[0];
#pragma unroll
    for (int mt = 0; mt < 2; ++mt) {
        float partial[4] = {0.f, 0.f, 0.f, 0.f};
#pragma unroll
        for (int nt = 0; nt < 4; ++nt) {
            int col = nt * 16 + l16;
            float b = br1[col];
            float w = Wr2[col];
#pragma unroll
            for (int r = 0; r < 4; ++r) partial[r] += sp1(acc[mt][nt][r] + b) * w;
        }
#pragma unroll
        for (int r = 0; r < 4; ++r) {
            float v = partial[r];
            v += __shfl_xor(v, 1); v += __shfl_xor(v, 2);
            v += __shfl_xor(v, 4); v += __shfl_xor(v, 8);
            if (l16 == 0) {
                int row = rb0 + mt * 64 + q * 4 + r;
                if (row < N_NODES) atomicAdd(&out[graph_ids[row]], v + brr);
            }
        }
    }
}

extern "C" void kernel_launch(void* const* d_in, const int* in_sizes, int n_in,
                              void* d_out, int out_size, void* d_ws, size_t ws_size,
                              hipStream_t stream) {
    const int* atom_type   = (const int*)d_in[0];
    const int* src         = (const int*)d_in[1];
    const int* dst         = (const int*)d_in[2];
    const int* graph_ids   = (const int*)d_in[3];
    const float* dist      = (const float*)d_in[4];
    const float* node_emb  = (const float*)d_in[5];
    const float* W_n1 = (const float*)d_in[6];  const float* b_n1 = (const float*)d_in[7];
    const float* W_c1 = (const float*)d_in[8];  const float* b_c1 = (const float*)d_in[9];
    const float* W_c2 = (const float*)d_in[10]; const float* b_c2 = (const float*)d_in[11];
    const float* W_c3 = (const float*)d_in[12]; const float* b_c3 = (const float*)d_in[13];
    const float* W_n2 = (const float*)d_in[14]; const float* b_n2 = (const float*)d_in[15];
    const float* W_n3 = (const float*)d_in[16]; const float* b_n3 = (const float*)d_in[17];
    const float* W_r1 = (const float*)d_in[18]; const float* b_r1 = (const float*)d_in[19];
    const float* W_r2 = (const float*)d_in[20]; const float* b_r2 = (const float*)d_in[21];
    float* out = (float*)d_out;

    size_t ND = (size_t)N_NODES * DIM;   // 7,680,000
    // uint2 meta
    uint2* meta   = (uint2*)d_ws;                       // N_EDGES
    // int region
    int* offsets  = (int*)(meta + N_EDGES);             // 60008 (padded)
    int* counts   = offsets + 60008;                    // 60000
    int* cnt2     = counts + N_NODES;                   // 60000
    int* bsums    = cnt2 + N_NODES;                     // 128 (padded)
    unsigned int* packed = (unsigned int*)(bsums + 128);  // 3*NBINS*128
    // ushort region
    unsigned short* hb0    = (unsigned short*)(packed + (size_t)3 * NBINS * DIM);
    unsigned short* hb1    = hb0 + ND;
    unsigned short* hb2    = hb1 + ND;
    unsigned short* hb3    = hb2 + ND;
    unsigned short* gb     = hb3 + ND;
    unsigned short* nodeb  = gb + ND;
    unsigned short* tableb = nodeb + ND;                // 3*(NBINS+1)*128
    unsigned short* WtF    = tableb + (size_t)3 * (NBINS + 1) * DIM;  // 9*16384
    unsigned short* Wr1tF  = WtF + 9 * 16384;           // 32768

    unsigned short* hbp[4] = {hb0, hb1, hb2, hb3};

    hipMemsetAsync(out, 0, B_GRAPHS * sizeof(float), stream);
    hipMemsetAsync(counts, 0, (2 * N_NODES + 128) * sizeof(int), stream);

    // one-time setup (tables depend only on weights)
    k_conv<<<(9 * 16384 + 32768 + 255) / 256, 256, 0, stream>>>(
        W_n1, W_n2, W_n3, W_r1, WtF, Wr1tF);
    k_embed<<<(N_NODES * DIM) / 256, 256, 0, stream>>>(atom_type, node_emb, hb0);
    k_table_all<<<3 * (NBINS + 1), DIM, 0, stream>>>(
        W_c1, b_c1, W_c2, b_c2, W_c3, b_c3, tableb);
    k_pack_all<<<(3 * NBINS * DIM) / 256, 256, 0, stream>>>(tableb, packed);

    // CSR build (dst-sorted edge meta)
    k_hist<<<(N_EDGES + 255) / 256, 256, 0, stream>>>(dst, counts);
    k_bsum<<<NCHUNK, 256, 0, stream>>>(counts, bsums);
    k_scan_b<<<1, 128, 0, stream>>>(bsums);
    k_scan_final<<<NCHUNK, 256, 0, stream>>>(counts, bsums, offsets);
    k_fill<<<(N_EDGES + 255) / 256, 256, 0, stream>>>(src, dst, dist, offsets, cnt2, meta);

    int gblocks = (N_NODES + 63) / 64;      // 938
    int rblocks = (N_NODES + 127) / 128;    // 469
    // layer 0's g from standalone GEMM; layers 1,2 g fused into node_update
    k_gemm_g<<<gblocks, 256, 0, stream>>>(hb0, WtF, b_n1, gb);
    for (int i = 0; i < NLAYERS; ++i) {
        k_gather<<<N_NODES / 4, 256, 0, stream>>>(
            offsets, meta, packed + (size_t)i * NBINS * DIM, gb, nodeb);
        int do_g = (i < NLAYERS - 1) ? 1 : 0;
        k_node_update<<<gblocks, 256, 0, stream>>>(
            nodeb, WtF + (size_t)(3 + i) * 16384, b_n2 + (size_t)i * DIM,
            WtF + (size_t)(6 + i) * 16384, b_n3 + (size_t)i * DIM,
            hbp[i], hbp[i + 1],
            WtF + (size_t)(i + 1) * 16384, b_n1 + (size_t)(i + 1 < 3 ? i + 1 : 0) * DIM,
            gb, do_g);
    }
    k_readout<<<rblocks, 256, 0, stream>>>(
        hb0, hb1, hb2, hb3, Wr1tF, b_r1, W_r2, b_r2, graph_ids, out);
}